// Round 4
// baseline (124.648 us; speedup 1.0000x reference)
//
#include <hip/hip_runtime.h>
#include <hip/hip_bf16.h>

#define NN 2048
typedef unsigned short u16;
typedef unsigned long long u64;
typedef __attribute__((ext_vector_type(8))) short short8;
typedef __attribute__((ext_vector_type(4))) float f32x4;

// fp32 -> bf16 bits, RNE (scalar path)
__device__ __forceinline__ unsigned bfb(float x) {
    unsigned u = __float_as_uint(x);
    return (u + 0x7FFFu + ((u >> 16) & 1u)) >> 16;
}
// packed pair via HW cvt (identical RNE bits, 1 instr)
__device__ __forceinline__ unsigned pk2(float a, float b) {
    unsigned r;
    asm("v_cvt_pk_bf16_f32 %0, %1, %2" : "=v"(r) : "v"(a), "v"(b));
    return r;
}

// ---------------- prep: adj bitmask + bf16 conversions (known-good round-1 structure) ----------------
__global__ __launch_bounds__(256) void prep(const float* __restrict__ x,
                                            const float* __restrict__ W1,
                                            const float* __restrict__ W2,
                                            const int* __restrict__ adj,
                                            u16* __restrict__ xb, u16* __restrict__ w1t,
                                            u16* __restrict__ w2t, u64* __restrict__ ab) {
    const int b = blockIdx.x;
    const int tid = threadIdx.x;
    if (b < 2048) {                          // adj bits: 8 ballot-units per block
#pragma unroll
        for (int k = 0; k < 8; ++k) {
            int t = (b * 8 + k) * 256 + tid;
            int W = t >> 6, lane = t & 63;
            int i = W >> 5, jw = W & 31;
            int a = adj[(size_t)i * NN + jw * 64 + lane];
            u64 mk = __ballot(a != 0);
            if (lane == 0) ab[(size_t)i * 32 + jw] = mk;
        }
    } else if (b < 2048 + 256) {             // x: 2048x512 -> bf16
#pragma unroll
        for (int k = 0; k < 4; ++k) {
            int t = ((b - 2048) * 4 + k) * 256 + tid;
            float4 v = ((const float4*)x)[t];
            uint2 o;
            o.x = pk2(v.x, v.y);
            o.y = pk2(v.z, v.w);
            ((uint2*)xb)[t] = o;
        }
    } else if (b < 2048 + 256 + 128) {       // w1t[c][k] = W1[k][c]
#pragma unroll
        for (int k = 0; k < 4; ++k) {
            int u = ((b - 2304) * 4 + k) * 256 + tid;
            int c = u >> 9, kk = u & 511;
            w1t[u] = (u16)bfb(W1[(size_t)kk * 256 + c]);
        }
    } else {                                 // w2t[c][k] = W2[k][c]
#pragma unroll
        for (int k = 0; k < 4; ++k) {
            int u = ((b - 2432) * 4 + k) * 256 + tid;
            int c = u >> 8, kk = u & 255;
            w2t[u] = (u16)bfb(W2[(size_t)kk * 128 + c]);
        }
    }
}

// ---------------- gemm1: 16x32 tile, K=512, LDS-staged from compact bf16 (xb, w1t).
// XCD-aware mapping: bid&7 selects rt-slice so each XCD's L2 holds xb-slice(256KB)+w1t(256KB). ----------------
__global__ __launch_bounds__(256) void gemm1(const u16* __restrict__ xb,   // [2048][512]
                                             const u16* __restrict__ w1t,  // [256][512]
                                             const float* __restrict__ al,
                                             const float* __restrict__ ar,
                                             u16* __restrict__ GT,         // [256][2048]
                                             float* __restrict__ el,       // [2048][8]
                                             float* __restrict__ ert) {    // [8][2048]
    const int bid = blockIdx.x;
    const int xcd = bid & 7, idx = bid >> 3;
    const int rt = xcd * 16 + (idx & 15), cs = idx >> 4;
    const int i0 = rt * 16;
    const int t = threadIdx.x, lane = t & 63, w = t >> 6;
    const int q = lane >> 4, n = lane & 15;
    const int ct = w & 1, kh = w >> 1;
    __shared__ __align__(16) u16 As[16][520];   // ^swz layout
    __shared__ __align__(16) u16 Bs[32][520];
    __shared__ float osh[2][16][16];
    __shared__ float pel[2][16], per_[2][16];

    // stage A: rows i0..i0+15 of xb (16KB), coalesced uint2, conflict-free (half-row per wave)
    {
        const uint2* xs = (const uint2*)(xb + (size_t)i0 * 512);
#pragma unroll
        for (int j = 0; j < 8; ++j) {
            uint2 v = xs[j * 256 + t];
            int e = (j * 256 + t) * 4;
            int r = e >> 9, k = e & 511;
            *(uint2*)&As[r][k ^ ((r & 7) << 3)] = v;
        }
    }
    // stage B: rows cs*32..+31 of w1t (32KB), same pattern
    {
        const uint2* bsrc = (const uint2*)(w1t + (size_t)cs * 32 * 512);
#pragma unroll
        for (int j = 0; j < 16; ++j) {
            uint2 v = bsrc[j * 256 + t];
            int e = (j * 256 + t) * 4;
            int r = e >> 9, k = e & 511;
            *(uint2*)&Bs[r][k ^ ((r & 7) << 3)] = v;
        }
    }
    __syncthreads();

    const int an = n, bn = ct * 16 + n;
    const int k0 = kh * 256 + q * 8;
    f32x4 acc = {0.f, 0.f, 0.f, 0.f};
#pragma unroll
    for (int ks = 0; ks < 8; ++ks) {
        short8 a = *(const short8*)&As[an][(k0 + ks * 32) ^ ((an & 7) << 3)];
        short8 bb = *(const short8*)&Bs[bn][(k0 + ks * 32) ^ ((bn & 7) << 3)];
        acc = __builtin_amdgcn_mfma_f32_16x16x32_bf16(a, bb, acc, 0, 0, 0);
    }
    if (kh == 1) {
#pragma unroll
        for (int r = 0; r < 4; ++r) osh[ct][q * 4 + r][n] = acc[r];
    }
    __syncthreads();
    if (kh == 0) {
#pragma unroll
        for (int r = 0; r < 4; ++r) acc[r] += osh[ct][q * 4 + r][n];
        uint2 g0;
        g0.x = pk2(acc[0], acc[1]);
        g0.y = pk2(acc[2], acc[3]);
        *(uint2*)&GT[(size_t)(cs * 32 + ct * 16 + n) * NN + i0 + q * 4] = g0;
        const float alv = al[ct * 16 + n], arv = ar[ct * 16 + n];
#pragma unroll
        for (int r = 0; r < 4; ++r) {
            float ve = acc[r] * alv, vr = acc[r] * arv;
#pragma unroll
            for (int off = 1; off <= 8; off <<= 1) {
                ve += __shfl_xor(ve, off);
                vr += __shfl_xor(vr, off);
            }
            if (n == 0) { pel[ct][q * 4 + r] = ve; per_[ct][q * 4 + r] = vr; }
        }
    }
    __syncthreads();
    if (t < 16) {
        el[(size_t)(i0 + t) * 8 + cs] = pel[0][t] + pel[1][t];
        ert[(size_t)cs * NN + i0 + t] = per_[0][t] + per_[1][t];
    }
}

// ---------------- gemm2: 16x32 tile, K=256, LDS-staged from hbb + w2t ----------------
__global__ __launch_bounds__(256) void gemm2(const u16* __restrict__ A,    // hbb [2048][256] bf16
                                             const u16* __restrict__ w2t,  // [128][256]
                                             const float* __restrict__ al,
                                             const float* __restrict__ ar,
                                             u16* __restrict__ GT,         // [128][2048]
                                             float* __restrict__ el2p,     // [4][2048]
                                             float* __restrict__ er2p) {   // [4][2048]
    const int i0 = blockIdx.x * 16, cs = blockIdx.y;
    const int t = threadIdx.x, lane = t & 63, w = t >> 6;
    const int q = lane >> 4, n = lane & 15;
    const int ct = w & 1, kh = w >> 1;
    __shared__ __align__(16) u16 As[16][264];
    __shared__ __align__(16) u16 Bs[32][264];
    __shared__ float osh[2][16][16];
    __shared__ float pel[2][16], per_[2][16];

    // stage A: rows i0..i0+15 of hbb, coalesced uint2; swizzled
    {
        const uint2* hs = (const uint2*)(A + (size_t)i0 * 256);
#pragma unroll
        for (int j = 0; j < 4; ++j) {
            uint2 v = hs[j * 256 + t];
            int e = (j * 256 + t) * 4;
            int r = e >> 8, k = e & 255;
            *(uint2*)&As[r][k ^ ((r & 7) << 3)] = v;
        }
    }
    // stage B: rows cs*32..+31 of w2t (16KB), coalesced uint2
    {
        const uint2* bsrc = (const uint2*)(w2t + (size_t)cs * 32 * 256);
#pragma unroll
        for (int j = 0; j < 8; ++j) {
            uint2 v = bsrc[j * 256 + t];
            int e = (j * 256 + t) * 4;
            int r = e >> 8, k = e & 255;
            *(uint2*)&Bs[r][k ^ ((r & 7) << 3)] = v;
        }
    }
    __syncthreads();

    const int an = n, bn = ct * 16 + n;
    const int k0 = kh * 128 + q * 8;
    f32x4 acc = {0.f, 0.f, 0.f, 0.f};
#pragma unroll
    for (int ks = 0; ks < 4; ++ks) {
        short8 a = *(const short8*)&As[an][(k0 + ks * 32) ^ ((an & 7) << 3)];
        short8 bb = *(const short8*)&Bs[bn][(k0 + ks * 32) ^ ((bn & 7) << 3)];
        acc = __builtin_amdgcn_mfma_f32_16x16x32_bf16(a, bb, acc, 0, 0, 0);
    }
    if (kh == 1) {
#pragma unroll
        for (int r = 0; r < 4; ++r) osh[ct][q * 4 + r][n] = acc[r];
    }
    __syncthreads();
    if (kh == 0) {
#pragma unroll
        for (int r = 0; r < 4; ++r) acc[r] += osh[ct][q * 4 + r][n];
        uint2 g0;
        g0.x = pk2(acc[0], acc[1]);
        g0.y = pk2(acc[2], acc[3]);
        *(uint2*)&GT[(size_t)(cs * 32 + ct * 16 + n) * NN + i0 + q * 4] = g0;
        const float alv = al[cs * 32 + ct * 16 + n], arv = ar[cs * 32 + ct * 16 + n];
#pragma unroll
        for (int r = 0; r < 4; ++r) {
            float ve = acc[r] * alv, vr = acc[r] * arv;
#pragma unroll
            for (int off = 1; off <= 8; off <<= 1) {
                ve += __shfl_xor(ve, off);
                vr += __shfl_xor(vr, off);
            }
            if (n == 0) { pel[ct][q * 4 + r] = ve; per_[ct][q * 4 + r] = vr; }
        }
    }
    __syncthreads();
    if (t < 16) {
        el2p[(size_t)cs * NN + i0 + t] = pel[0][t] + pel[1][t];
        er2p[(size_t)cs * NN + i0 + t] = per_[0][t] + per_[1][t];
    }
}

// ---------------- attn1: 16 rows x 2 heads (64 cols), 256-j tiles (8 phases), dbuf pl ----------------
__global__ __launch_bounds__(512, 4) void attn1(const float* __restrict__ el,      // [2048][8]
                                                const float* __restrict__ ert,     // [8][2048]
                                                const unsigned* __restrict__ ab32, // [2048][64]
                                                const u16* __restrict__ gbt,       // [256][2048]
                                                u16* __restrict__ hbb) {           // [2048][256]
    const int rt = blockIdx.x, sec = blockIdx.y;
    const int i0 = rt * 16, h0 = sec * 2;
    const int t = threadIdx.x, lane = t & 63, w = t >> 6;
    const int q = lane >> 4, n = lane & 15;
    const int m = t >> 5, jq = t & 31;
    const int hl = w >> 2, ch = (w >> 1) & 1, kf2 = w & 1;

    __shared__ u16 ersb[2][2048];                     // bf16 er
    __shared__ __align__(16) u16 pl[2][2][16][264];   // [buf][h][m][k]
    __shared__ unsigned absh[16][64];
    __shared__ float psum_sh[16][2];
    __shared__ float osh[2][2][16][16];
    __shared__ float wmax[2][8];
    __shared__ float mxsh[2];

    float4 v0 = *(const float4*)(ert + (size_t)h0 * NN + t * 4);
    float4 v1 = *(const float4*)(ert + (size_t)(h0 + 1) * NN + t * 4);
    uint2 c0, c1;
    c0.x = pk2(v0.x, v0.y); c0.y = pk2(v0.z, v0.w);
    c1.x = pk2(v1.x, v1.y); c1.y = pk2(v1.z, v1.w);
    *(uint2*)&ersb[0][t * 4] = c0;
    *(uint2*)&ersb[1][t * 4] = c1;
    float m0 = fmaxf(fmaxf(v0.x, v0.y), fmaxf(v0.z, v0.w));
    float m1 = fmaxf(fmaxf(v1.x, v1.y), fmaxf(v1.z, v1.w));
#pragma unroll
    for (int off = 32; off; off >>= 1) {
        m0 = fmaxf(m0, __shfl_xor(m0, off));
        m1 = fmaxf(m1, __shfl_xor(m1, off));
    }
    if (lane == 0) { wmax[0][w] = m0; wmax[1][w] = m1; }
    for (int c = t; c < 1024; c += 512)
        absh[c >> 6][c & 63] = ab32[(size_t)(i0 + (c >> 6)) * 64 + (c & 63)];
    __syncthreads();
    if (t < 2) {
        float mm = wmax[t][0];
#pragma unroll
        for (int ww = 1; ww < 8; ++ww) mm = fmaxf(mm, wmax[t][ww]);
        mxsh[t] = mm;
    }
    __syncthreads();

    float elv[2], mxv[2], ps[2];
#pragma unroll
    for (int h = 0; h < 2; ++h) {
        float e = el[(size_t)(i0 + m) * 8 + h0 + h];
        elv[h] = e;
        float mm = e + mxsh[h];
        mxv[h] = fmaxf(mm, 0.2f * mm);
        ps[h] = 0.f;
    }

    auto stage = [&](int tl, int nb) {
#pragma unroll
        for (int sub = 0; sub < 2; ++sub) {
            unsigned word = absh[m][tl * 8 + sub * 4 + (jq >> 3)];
            unsigned bits = (word >> ((jq & 7) * 4)) & 0xFu;
            const int jo = tl * 256 + sub * 128 + jq * 4;
            uint2 raw0 = *(const uint2*)&ersb[0][jo];
            uint2 raw1 = *(const uint2*)&ersb[1][jo];
#pragma unroll
            for (int h = 0; h < 2; ++h) {
                uint2 raw = h ? raw1 : raw0;
                float e0 = __uint_as_float(raw.x << 16);
                float e1 = __uint_as_float(raw.x & 0xFFFF0000u);
                float e2 = __uint_as_float(raw.y << 16);
                float e3 = __uint_as_float(raw.y & 0xFFFF0000u);
                float s0 = elv[h] + e0, s1 = elv[h] + e1, s2 = elv[h] + e2, s3 = elv[h] + e3;
                s0 = fmaxf(s0, 0.2f * s0) - mxv[h];
                s1 = fmaxf(s1, 0.2f * s1) - mxv[h];
                s2 = fmaxf(s2, 0.2f * s2) - mxv[h];
                s3 = fmaxf(s3, 0.2f * s3) - mxv[h];
                float p0 = (bits & 1u) ? __expf(s0) : 0.f;
                float p1 = (bits & 2u) ? __expf(s1) : 0.f;
                float p2 = (bits & 4u) ? __expf(s2) : 0.f;
                float p3 = (bits & 8u) ? __expf(s3) : 0.f;
                ps[h] += (p0 + p1) + (p2 + p3);
                uint2 pkv;
                pkv.x = pk2(p0, p1);
                pkv.y = pk2(p2, p3);
                *(uint2*)&pl[nb][h][m][sub * 128 + jq * 4] = pkv;
            }
        }
    };

    const int col = sec * 64 + hl * 32 + ch * 16 + n;
    const u16* gb = gbt + (size_t)col * NN + kf2 * 128 + q * 8;
    short8 bc0 = *(const short8*)gb;
    short8 bc1 = *(const short8*)(gb + 32);
    short8 bc2 = *(const short8*)(gb + 64);
    short8 bc3 = *(const short8*)(gb + 96);
    f32x4 acc = {0.f, 0.f, 0.f, 0.f};

    stage(0, 0);
    __syncthreads();

    for (int tile = 0; tile < 8; ++tile) {
        short8 bn0 = bc0, bn1 = bc1, bn2 = bc2, bn3 = bc3;
        if (tile < 7) {
            const u16* gq = gb + (tile + 1) * 256;
            bn0 = *(const short8*)gq;
            bn1 = *(const short8*)(gq + 32);
            bn2 = *(const short8*)(gq + 64);
            bn3 = *(const short8*)(gq + 96);
        }
        const u16* ap = &pl[tile & 1][hl][n][kf2 * 128 + q * 8];
        short8 a0 = *(const short8*)ap;
        short8 a1 = *(const short8*)(ap + 32);
        short8 a2 = *(const short8*)(ap + 64);
        short8 a3 = *(const short8*)(ap + 96);
        acc = __builtin_amdgcn_mfma_f32_16x16x32_bf16(a0, bc0, acc, 0, 0, 0);
        acc = __builtin_amdgcn_mfma_f32_16x16x32_bf16(a1, bc1, acc, 0, 0, 0);
        acc = __builtin_amdgcn_mfma_f32_16x16x32_bf16(a2, bc2, acc, 0, 0, 0);
        acc = __builtin_amdgcn_mfma_f32_16x16x32_bf16(a3, bc3, acc, 0, 0, 0);
        if (tile < 7) stage(tile + 1, (tile + 1) & 1);
        bc0 = bn0; bc1 = bn1; bc2 = bn2; bc3 = bn3;
        __syncthreads();
    }

#pragma unroll
    for (int h = 0; h < 2; ++h) {
        float v = ps[h];
#pragma unroll
        for (int off = 16; off; off >>= 1) v += __shfl_down(v, off, 32);
        if (jq == 0) psum_sh[m][h] = v;
    }
    if (kf2 == 1) {
#pragma unroll
        for (int r = 0; r < 4; ++r) osh[hl][ch][q * 4 + r][n] = acc[r];
    }
    __syncthreads();
    if (kf2 == 0) {
#pragma unroll
        for (int r = 0; r < 4; ++r) {
            int mr = q * 4 + r;
            float o = (acc[r] + osh[hl][ch][mr][n]) / psum_sh[mr][hl];
            o = o > 0.f ? o : (__expf(o) - 1.f); // ELU
            hbb[(size_t)(i0 + mr) * 256 + col] = (u16)bfb(o);
        }
    }
}

// ---------------- attn2: 16 rows x 64 cols (1 head), 256-j tiles (8 phases), dbuf ----------------
__global__ __launch_bounds__(512) void attn2(const float* __restrict__ el2p,    // [4][2048]
                                             const float* __restrict__ er2p,    // [4][2048]
                                             const unsigned* __restrict__ ab32,
                                             const u16* __restrict__ gbt,       // [128][2048]
                                             float* __restrict__ out) {         // [2048][128]
    const int rt = blockIdx.x, sec = blockIdx.y;
    const int i0 = rt * 16;
    const int t = threadIdx.x, lane = t & 63, w = t >> 6;
    const int q = lane >> 4, n = lane & 15;
    const int m = t >> 5, jq = t & 31;
    const int ct = w >> 1, kf2 = w & 1;

    __shared__ u16 ersb[2048];
    __shared__ __align__(16) u16 pl[2][16][264];
    __shared__ unsigned absh[16][64];
    __shared__ float psum_sh[16];
    __shared__ float osh[4][16][16];
    __shared__ float wmax[8];
    __shared__ float mxsh;

    float4 a0 = *(const float4*)(er2p + t * 4);
    float4 a1 = *(const float4*)(er2p + NN + t * 4);
    float4 a2 = *(const float4*)(er2p + 2 * NN + t * 4);
    float4 a3 = *(const float4*)(er2p + 3 * NN + t * 4);
    float4 v0;
    v0.x = ((a0.x + a1.x) + (a2.x + a3.x));
    v0.y = ((a0.y + a1.y) + (a2.y + a3.y));
    v0.z = ((a0.z + a1.z) + (a2.z + a3.z));
    v0.w = ((a0.w + a1.w) + (a2.w + a3.w));
    uint2 c0;
    c0.x = pk2(v0.x, v0.y); c0.y = pk2(v0.z, v0.w);
    *(uint2*)&ersb[t * 4] = c0;
    float m0 = fmaxf(fmaxf(v0.x, v0.y), fmaxf(v0.z, v0.w));
#pragma unroll
    for (int off = 32; off; off >>= 1) m0 = fmaxf(m0, __shfl_xor(m0, off));
    if (lane == 0) wmax[w] = m0;
    for (int c = t; c < 1024; c += 512)
        absh[c >> 6][c & 63] = ab32[(size_t)(i0 + (c >> 6)) * 64 + (c & 63)];
    __syncthreads();
    if (t == 0) {
        float mm = wmax[0];
#pragma unroll
        for (int ww = 1; ww < 8; ++ww) mm = fmaxf(mm, wmax[ww]);
        mxsh = mm;
    }
    __syncthreads();

    const float elv = el2p[i0 + m] + el2p[NN + i0 + m] + el2p[2 * NN + i0 + m] + el2p[3 * NN + i0 + m];
    float mm2 = elv + mxsh;
    const float mxv = fmaxf(mm2, 0.2f * mm2);
    float ps = 0.f;

    auto stage = [&](int tl, int nb) {
#pragma unroll
        for (int sub = 0; sub < 2; ++sub) {
            unsigned word = absh[m][tl * 8 + sub * 4 + (jq >> 3)];
            unsigned bits = (word >> ((jq & 7) * 4)) & 0xFu;
            const int jo = tl * 256 + sub * 128 + jq * 4;
            uint2 raw = *(const uint2*)&ersb[jo];
            float e0 = __uint_as_float(raw.x << 16);
            float e1 = __uint_as_float(raw.x & 0xFFFF0000u);
            float e2 = __uint_as_float(raw.y << 16);
            float e3 = __uint_as_float(raw.y & 0xFFFF0000u);
            float s0 = elv + e0, s1 = elv + e1, s2 = elv + e2, s3 = elv + e3;
            s0 = fmaxf(s0, 0.2f * s0) - mxv;
            s1 = fmaxf(s1, 0.2f * s1) - mxv;
            s2 = fmaxf(s2, 0.2f * s2) - mxv;
            s3 = fmaxf(s3, 0.2f * s3) - mxv;
            float p0 = (bits & 1u) ? __expf(s0) : 0.f;
            float p1 = (bits & 2u) ? __expf(s1) : 0.f;
            float p2 = (bits & 4u) ? __expf(s2) : 0.f;
            float p3 = (bits & 8u) ? __expf(s3) : 0.f;
            ps += (p0 + p1) + (p2 + p3);
            uint2 pkv;
            pkv.x = pk2(p0, p1);
            pkv.y = pk2(p2, p3);
            *(uint2*)&pl[nb][m][sub * 128 + jq * 4] = pkv;
        }
    };

    const int col = sec * 64 + ct * 16 + n;
    const u16* gb = gbt + (size_t)col * NN + kf2 * 128 + q * 8;
    short8 bc0 = *(const short8*)gb;
    short8 bc1 = *(const short8*)(gb + 32);
    short8 bc2 = *(const short8*)(gb + 64);
    short8 bc3 = *(const short8*)(gb + 96);
    f32x4 acc = {0.f, 0.f, 0.f, 0.f};

    stage(0, 0);
    __syncthreads();

    for (int tile = 0; tile < 8; ++tile) {
        short8 bn0 = bc0, bn1 = bc1, bn2 = bc2, bn3 = bc3;
        if (tile < 7) {
            const u16* gq = gb + (tile + 1) * 256;
            bn0 = *(const short8*)gq;
            bn1 = *(const short8*)(gq + 32);
            bn2 = *(const short8*)(gq + 64);
            bn3 = *(const short8*)(gq + 96);
        }
        const u16* ap = &pl[tile & 1][n][kf2 * 128 + q * 8];
        short8 a0v = *(const short8*)ap;
        short8 a1v = *(const short8*)(ap + 32);
        short8 a2v = *(const short8*)(ap + 64);
        short8 a3v = *(const short8*)(ap + 96);
        acc = __builtin_amdgcn_mfma_f32_16x16x32_bf16(a0v, bc0, acc, 0, 0, 0);
        acc = __builtin_amdgcn_mfma_f32_16x16x32_bf16(a1v, bc1, acc, 0, 0, 0);
        acc = __builtin_amdgcn_mfma_f32_16x16x32_bf16(a2v, bc2, acc, 0, 0, 0);
        acc = __builtin_amdgcn_mfma_f32_16x16x32_bf16(a3v, bc3, acc, 0, 0, 0);
        if (tile < 7) stage(tile + 1, (tile + 1) & 1);
        bc0 = bn0; bc1 = bn1; bc2 = bn2; bc3 = bn3;
        __syncthreads();
    }

#pragma unroll
    for (int off = 16; off; off >>= 1) ps += __shfl_down(ps, off, 32);
    if (jq == 0) psum_sh[m] = ps;
    if (kf2 == 1) {
#pragma unroll
        for (int r = 0; r < 4; ++r) osh[ct][q * 4 + r][n] = acc[r];
    }
    __syncthreads();
    if (kf2 == 0) {
#pragma unroll
        for (int r = 0; r < 4; ++r) {
            int mr = q * 4 + r;
            out[(size_t)(i0 + mr) * 128 + col] = (acc[r] + osh[ct][mr][n]) / psum_sh[mr];
        }
    }
}

extern "C" void kernel_launch(void* const* d_in, const int* in_sizes, int n_in,
                              void* d_out, int out_size, void* d_ws, size_t ws_size,
                              hipStream_t stream) {
    const float* x   = (const float*)d_in[0];
    const float* W1  = (const float*)d_in[1];
    const float* a1l = (const float*)d_in[2];
    const float* a1r = (const float*)d_in[3];
    const float* W2  = (const float*)d_in[4];
    const float* a2l = (const float*)d_in[5];
    const float* a2r = (const float*)d_in[6];
    const int* adj = (const int*)d_in[7];

    char* p = (char*)d_ws;
    u16* xb    = (u16*)p;            p += (size_t)NN * 512 * 2;
    u16* w1t   = (u16*)p;            p += (size_t)256 * 512 * 2;
    u16* w2t   = (u16*)p;            p += (size_t)128 * 256 * 2;
    unsigned* abits = (unsigned*)p;  p += (size_t)NN * 64 * 4;
    u16* gbt1  = (u16*)p;            p += (size_t)256 * NN * 2;
    u16* hbb   = (u16*)p;            p += (size_t)NN * 256 * 2;
    u16* gbt2  = (u16*)p;            p += (size_t)128 * NN * 2;
    float* el1 = (float*)p;          p += (size_t)NN * 8 * 4;
    float* ert1 = (float*)p;         p += (size_t)8 * NN * 4;
    float* el2p = (float*)p;         p += (size_t)4 * NN * 4;
    float* er2p = (float*)p;         p += (size_t)4 * NN * 4;

    prep<<<2464, 256, 0, stream>>>(x, W1, W2, adj, xb, w1t, w2t, (u64*)abits);

    gemm1<<<1024, 256, 0, stream>>>(xb, w1t, a1l, a1r, gbt1, el1, ert1);
    attn1<<<dim3(128, 4), 512, 0, stream>>>(el1, ert1, abits, gbt1, hbb);

    gemm2<<<dim3(128, 4), 256, 0, stream>>>(hbb, w2t, a2l, a2r, gbt2, el2p, er2p);
    attn2<<<dim3(128, 2), 512, 0, stream>>>(el2p, er2p, abits, gbt2, (float*)d_out);
}

// Round 5
// 122.647 us; speedup vs baseline: 1.0163x; 1.0163x over previous
//
#include <hip/hip_runtime.h>
#include <hip/hip_bf16.h>

#define NN 2048
typedef unsigned short u16;
typedef unsigned long long u64;
typedef __attribute__((ext_vector_type(8))) short short8;
typedef __attribute__((ext_vector_type(4))) float f32x4;

// fp32 -> bf16 bits, RNE (scalar path)
__device__ __forceinline__ unsigned bfb(float x) {
    unsigned u = __float_as_uint(x);
    return (u + 0x7FFFu + ((u >> 16) & 1u)) >> 16;
}
// packed pair via HW cvt (identical RNE bits, 1 instr)
__device__ __forceinline__ unsigned pk2(float a, float b) {
    unsigned r;
    asm("v_cvt_pk_bf16_f32 %0, %1, %2" : "=v"(r) : "v"(a), "v"(b));
    return r;
}

// ---------------- prep: bf16 conversions only (adj handled inline in attn kernels) ----------------
__global__ __launch_bounds__(256) void prep(const float* __restrict__ x,
                                            const float* __restrict__ W1,
                                            const float* __restrict__ W2,
                                            u16* __restrict__ xb, u16* __restrict__ w1t,
                                            u16* __restrict__ w2t) {
    const int b = blockIdx.x;
    const int tid = threadIdx.x;
    if (b < 256) {                           // x: 2048x512 -> bf16
#pragma unroll
        for (int k = 0; k < 4; ++k) {
            int t = (b * 4 + k) * 256 + tid;
            float4 v = ((const float4*)x)[t];
            uint2 o;
            o.x = pk2(v.x, v.y);
            o.y = pk2(v.z, v.w);
            ((uint2*)xb)[t] = o;
        }
    } else if (b < 256 + 128) {              // w1t[c][k] = W1[k][c]
#pragma unroll
        for (int k = 0; k < 4; ++k) {
            int u = ((b - 256) * 4 + k) * 256 + tid;
            int c = u >> 9, kk = u & 511;
            w1t[u] = (u16)bfb(W1[(size_t)kk * 256 + c]);
        }
    } else {                                 // w2t[c][k] = W2[k][c]
#pragma unroll
        for (int k = 0; k < 4; ++k) {
            int u = ((b - 384) * 4 + k) * 256 + tid;
            int c = u >> 8, kk = u & 255;
            w2t[u] = (u16)bfb(W2[(size_t)kk * 128 + c]);
        }
    }
}

// ---------------- gemm1: 16x32 tile, K=512, LDS-staged from compact bf16 (xb, w1t) ----------------
__global__ __launch_bounds__(256) void gemm1(const u16* __restrict__ xb,   // [2048][512]
                                             const u16* __restrict__ w1t,  // [256][512]
                                             const float* __restrict__ al,
                                             const float* __restrict__ ar,
                                             u16* __restrict__ GT,         // [256][2048]
                                             float* __restrict__ el,       // [2048][8]
                                             float* __restrict__ ert) {    // [8][2048]
    const int bid = blockIdx.x;
    const int xcd = bid & 7, idx = bid >> 3;
    const int rt = xcd * 16 + (idx & 15), cs = idx >> 4;
    const int i0 = rt * 16;
    const int t = threadIdx.x, lane = t & 63, w = t >> 6;
    const int q = lane >> 4, n = lane & 15;
    const int ct = w & 1, kh = w >> 1;
    __shared__ __align__(16) u16 As[16][520];   // ^swz layout
    __shared__ __align__(16) u16 Bs[32][520];
    __shared__ float osh[2][16][16];
    __shared__ float pel[2][16], per_[2][16];

    // stage A: rows i0..i0+15 of xb (16KB), coalesced uint2, conflict-free (half-row per wave)
    {
        const uint2* xs = (const uint2*)(xb + (size_t)i0 * 512);
#pragma unroll
        for (int j = 0; j < 8; ++j) {
            uint2 v = xs[j * 256 + t];
            int e = (j * 256 + t) * 4;
            int r = e >> 9, k = e & 511;
            *(uint2*)&As[r][k ^ ((r & 7) << 3)] = v;
        }
    }
    // stage B: rows cs*32..+31 of w1t (32KB), same pattern
    {
        const uint2* bsrc = (const uint2*)(w1t + (size_t)cs * 32 * 512);
#pragma unroll
        for (int j = 0; j < 16; ++j) {
            uint2 v = bsrc[j * 256 + t];
            int e = (j * 256 + t) * 4;
            int r = e >> 9, k = e & 511;
            *(uint2*)&Bs[r][k ^ ((r & 7) << 3)] = v;
        }
    }
    __syncthreads();

    const int an = n, bn = ct * 16 + n;
    const int k0 = kh * 256 + q * 8;
    f32x4 acc = {0.f, 0.f, 0.f, 0.f};
#pragma unroll
    for (int ks = 0; ks < 8; ++ks) {
        short8 a = *(const short8*)&As[an][(k0 + ks * 32) ^ ((an & 7) << 3)];
        short8 bb = *(const short8*)&Bs[bn][(k0 + ks * 32) ^ ((bn & 7) << 3)];
        acc = __builtin_amdgcn_mfma_f32_16x16x32_bf16(a, bb, acc, 0, 0, 0);
    }
    if (kh == 1) {
#pragma unroll
        for (int r = 0; r < 4; ++r) osh[ct][q * 4 + r][n] = acc[r];
    }
    __syncthreads();
    if (kh == 0) {
#pragma unroll
        for (int r = 0; r < 4; ++r) acc[r] += osh[ct][q * 4 + r][n];
        uint2 g0;
        g0.x = pk2(acc[0], acc[1]);
        g0.y = pk2(acc[2], acc[3]);
        *(uint2*)&GT[(size_t)(cs * 32 + ct * 16 + n) * NN + i0 + q * 4] = g0;
        const float alv = al[ct * 16 + n], arv = ar[ct * 16 + n];
#pragma unroll
        for (int r = 0; r < 4; ++r) {
            float ve = acc[r] * alv, vr = acc[r] * arv;
#pragma unroll
            for (int off = 1; off <= 8; off <<= 1) {
                ve += __shfl_xor(ve, off);
                vr += __shfl_xor(vr, off);
            }
            if (n == 0) { pel[ct][q * 4 + r] = ve; per_[ct][q * 4 + r] = vr; }
        }
    }
    __syncthreads();
    if (t < 16) {
        el[(size_t)(i0 + t) * 8 + cs] = pel[0][t] + pel[1][t];
        ert[(size_t)cs * NN + i0 + t] = per_[0][t] + per_[1][t];
    }
}

// ---------------- gemm2: 16x32 tile, K=256, LDS-staged from hbb + w2t ----------------
__global__ __launch_bounds__(256) void gemm2(const u16* __restrict__ A,    // hbb [2048][256] bf16
                                             const u16* __restrict__ w2t,  // [128][256]
                                             const float* __restrict__ al,
                                             const float* __restrict__ ar,
                                             u16* __restrict__ GT,         // [128][2048]
                                             float* __restrict__ el2p,     // [4][2048]
                                             float* __restrict__ er2p) {   // [4][2048]
    const int i0 = blockIdx.x * 16, cs = blockIdx.y;
    const int t = threadIdx.x, lane = t & 63, w = t >> 6;
    const int q = lane >> 4, n = lane & 15;
    const int ct = w & 1, kh = w >> 1;
    __shared__ __align__(16) u16 As[16][264];
    __shared__ __align__(16) u16 Bs[32][264];
    __shared__ float osh[2][16][16];
    __shared__ float pel[2][16], per_[2][16];

    {
        const uint2* hs = (const uint2*)(A + (size_t)i0 * 256);
#pragma unroll
        for (int j = 0; j < 4; ++j) {
            uint2 v = hs[j * 256 + t];
            int e = (j * 256 + t) * 4;
            int r = e >> 8, k = e & 255;
            *(uint2*)&As[r][k ^ ((r & 7) << 3)] = v;
        }
    }
    {
        const uint2* bsrc = (const uint2*)(w2t + (size_t)cs * 32 * 256);
#pragma unroll
        for (int j = 0; j < 8; ++j) {
            uint2 v = bsrc[j * 256 + t];
            int e = (j * 256 + t) * 4;
            int r = e >> 8, k = e & 255;
            *(uint2*)&Bs[r][k ^ ((r & 7) << 3)] = v;
        }
    }
    __syncthreads();

    const int an = n, bn = ct * 16 + n;
    const int k0 = kh * 128 + q * 8;
    f32x4 acc = {0.f, 0.f, 0.f, 0.f};
#pragma unroll
    for (int ks = 0; ks < 4; ++ks) {
        short8 a = *(const short8*)&As[an][(k0 + ks * 32) ^ ((an & 7) << 3)];
        short8 bb = *(const short8*)&Bs[bn][(k0 + ks * 32) ^ ((bn & 7) << 3)];
        acc = __builtin_amdgcn_mfma_f32_16x16x32_bf16(a, bb, acc, 0, 0, 0);
    }
    if (kh == 1) {
#pragma unroll
        for (int r = 0; r < 4; ++r) osh[ct][q * 4 + r][n] = acc[r];
    }
    __syncthreads();
    if (kh == 0) {
#pragma unroll
        for (int r = 0; r < 4; ++r) acc[r] += osh[ct][q * 4 + r][n];
        uint2 g0;
        g0.x = pk2(acc[0], acc[1]);
        g0.y = pk2(acc[2], acc[3]);
        *(uint2*)&GT[(size_t)(cs * 32 + ct * 16 + n) * NN + i0 + q * 4] = g0;
        const float alv = al[cs * 32 + ct * 16 + n], arv = ar[cs * 32 + ct * 16 + n];
#pragma unroll
        for (int r = 0; r < 4; ++r) {
            float ve = acc[r] * alv, vr = acc[r] * arv;
#pragma unroll
            for (int off = 1; off <= 8; off <<= 1) {
                ve += __shfl_xor(ve, off);
                vr += __shfl_xor(vr, off);
            }
            if (n == 0) { pel[ct][q * 4 + r] = ve; per_[ct][q * 4 + r] = vr; }
        }
    }
    __syncthreads();
    if (t < 16) {
        el2p[(size_t)cs * NN + i0 + t] = pel[0][t] + pel[1][t];
        er2p[(size_t)cs * NN + i0 + t] = per_[0][t] + per_[1][t];
    }
}

// ---------------- attn1: 16 rows x 2 heads, 256-j tiles (8 phases); adj nibbles inline ----------------
__global__ __launch_bounds__(512, 4) void attn1(const float* __restrict__ el,      // [2048][8]
                                                const float* __restrict__ ert,     // [8][2048]
                                                const int* __restrict__ adj,       // [2048][2048]
                                                const u16* __restrict__ gbt,       // [256][2048]
                                                u16* __restrict__ hbb) {           // [2048][256]
    const int rt = blockIdx.x, sec = blockIdx.y;
    const int i0 = rt * 16, h0 = sec * 2;
    const int t = threadIdx.x, lane = t & 63, w = t >> 6;
    const int q = lane >> 4, n = lane & 15;
    const int m = t >> 5, jq = t & 31;
    const int hl = w >> 2, ch = (w >> 1) & 1, kf2 = w & 1;

    __shared__ u16 ersb[2][2048];                     // bf16 er
    __shared__ __align__(16) u16 pl[2][2][16][264];   // [buf][h][m][k]
    __shared__ float psum_sh[16][2];
    __shared__ float osh[2][2][16][16];
    __shared__ float wmax[2][8];
    __shared__ float mxsh[2];

    float4 v0 = *(const float4*)(ert + (size_t)h0 * NN + t * 4);
    float4 v1 = *(const float4*)(ert + (size_t)(h0 + 1) * NN + t * 4);
    uint2 c0, c1;
    c0.x = pk2(v0.x, v0.y); c0.y = pk2(v0.z, v0.w);
    c1.x = pk2(v1.x, v1.y); c1.y = pk2(v1.z, v1.w);
    *(uint2*)&ersb[0][t * 4] = c0;
    *(uint2*)&ersb[1][t * 4] = c1;
    float m0 = fmaxf(fmaxf(v0.x, v0.y), fmaxf(v0.z, v0.w));
    float m1 = fmaxf(fmaxf(v1.x, v1.y), fmaxf(v1.z, v1.w));
#pragma unroll
    for (int off = 32; off; off >>= 1) {
        m0 = fmaxf(m0, __shfl_xor(m0, off));
        m1 = fmaxf(m1, __shfl_xor(m1, off));
    }
    if (lane == 0) { wmax[0][w] = m0; wmax[1][w] = m1; }
    __syncthreads();
    if (t < 2) {
        float mm = wmax[t][0];
#pragma unroll
        for (int ww = 1; ww < 8; ++ww) mm = fmaxf(mm, wmax[t][ww]);
        mxsh[t] = mm;
    }
    __syncthreads();

    float elv[2], mxv[2], ps[2];
#pragma unroll
    for (int h = 0; h < 2; ++h) {
        float e = el[(size_t)(i0 + m) * 8 + h0 + h];
        elv[h] = e;
        float mm = e + mxsh[h];
        mxv[h] = fmaxf(mm, 0.2f * mm);
        ps[h] = 0.f;
    }
    const int* adjrow = adj + (size_t)(i0 + m) * NN;

    auto stage = [&](int tl, int nb) {
        // issue both adj int4 loads first (independent; latency overlaps nibble/VALU work)
        int4 av0 = *(const int4*)(adjrow + tl * 256 + jq * 4);
        int4 av1 = *(const int4*)(adjrow + tl * 256 + 128 + jq * 4);
#pragma unroll
        for (int sub = 0; sub < 2; ++sub) {
            int4 av = sub ? av1 : av0;
            unsigned bits = (unsigned)(av.x != 0) | ((unsigned)(av.y != 0) << 1) |
                            ((unsigned)(av.z != 0) << 2) | ((unsigned)(av.w != 0) << 3);
            const int jo = tl * 256 + sub * 128 + jq * 4;
            uint2 raw0 = *(const uint2*)&ersb[0][jo];
            uint2 raw1 = *(const uint2*)&ersb[1][jo];
#pragma unroll
            for (int h = 0; h < 2; ++h) {
                uint2 raw = h ? raw1 : raw0;
                float e0 = __uint_as_float(raw.x << 16);
                float e1 = __uint_as_float(raw.x & 0xFFFF0000u);
                float e2 = __uint_as_float(raw.y << 16);
                float e3 = __uint_as_float(raw.y & 0xFFFF0000u);
                float s0 = elv[h] + e0, s1 = elv[h] + e1, s2 = elv[h] + e2, s3 = elv[h] + e3;
                s0 = fmaxf(s0, 0.2f * s0) - mxv[h];
                s1 = fmaxf(s1, 0.2f * s1) - mxv[h];
                s2 = fmaxf(s2, 0.2f * s2) - mxv[h];
                s3 = fmaxf(s3, 0.2f * s3) - mxv[h];
                float p0 = (bits & 1u) ? __expf(s0) : 0.f;
                float p1 = (bits & 2u) ? __expf(s1) : 0.f;
                float p2 = (bits & 4u) ? __expf(s2) : 0.f;
                float p3 = (bits & 8u) ? __expf(s3) : 0.f;
                ps[h] += (p0 + p1) + (p2 + p3);
                uint2 pkv;
                pkv.x = pk2(p0, p1);
                pkv.y = pk2(p2, p3);
                *(uint2*)&pl[nb][h][m][sub * 128 + jq * 4] = pkv;
            }
        }
    };

    const int col = sec * 64 + hl * 32 + ch * 16 + n;
    const u16* gb = gbt + (size_t)col * NN + kf2 * 128 + q * 8;
    short8 bc0 = *(const short8*)gb;
    short8 bc1 = *(const short8*)(gb + 32);
    short8 bc2 = *(const short8*)(gb + 64);
    short8 bc3 = *(const short8*)(gb + 96);
    f32x4 acc = {0.f, 0.f, 0.f, 0.f};

    stage(0, 0);
    __syncthreads();

    for (int tile = 0; tile < 8; ++tile) {
        short8 bn0 = bc0, bn1 = bc1, bn2 = bc2, bn3 = bc3;
        if (tile < 7) {
            const u16* gq = gb + (tile + 1) * 256;
            bn0 = *(const short8*)gq;
            bn1 = *(const short8*)(gq + 32);
            bn2 = *(const short8*)(gq + 64);
            bn3 = *(const short8*)(gq + 96);
        }
        const u16* ap = &pl[tile & 1][hl][n][kf2 * 128 + q * 8];
        short8 a0 = *(const short8*)ap;
        short8 a1 = *(const short8*)(ap + 32);
        short8 a2 = *(const short8*)(ap + 64);
        short8 a3 = *(const short8*)(ap + 96);
        acc = __builtin_amdgcn_mfma_f32_16x16x32_bf16(a0, bc0, acc, 0, 0, 0);
        acc = __builtin_amdgcn_mfma_f32_16x16x32_bf16(a1, bc1, acc, 0, 0, 0);
        acc = __builtin_amdgcn_mfma_f32_16x16x32_bf16(a2, bc2, acc, 0, 0, 0);
        acc = __builtin_amdgcn_mfma_f32_16x16x32_bf16(a3, bc3, acc, 0, 0, 0);
        if (tile < 7) stage(tile + 1, (tile + 1) & 1);
        bc0 = bn0; bc1 = bn1; bc2 = bn2; bc3 = bn3;
        __syncthreads();
    }

#pragma unroll
    for (int h = 0; h < 2; ++h) {
        float v = ps[h];
#pragma unroll
        for (int off = 16; off; off >>= 1) v += __shfl_down(v, off, 32);
        if (jq == 0) psum_sh[m][h] = v;
    }
    if (kf2 == 1) {
#pragma unroll
        for (int r = 0; r < 4; ++r) osh[hl][ch][q * 4 + r][n] = acc[r];
    }
    __syncthreads();
    if (kf2 == 0) {
#pragma unroll
        for (int r = 0; r < 4; ++r) {
            int mr = q * 4 + r;
            float o = (acc[r] + osh[hl][ch][mr][n]) / psum_sh[mr][hl];
            o = o > 0.f ? o : (__expf(o) - 1.f); // ELU
            hbb[(size_t)(i0 + mr) * 256 + col] = (u16)bfb(o);
        }
    }
}

// ---------------- attn2: 16 rows x 64 cols, 256-j tiles (8 phases); adj nibbles inline ----------------
__global__ __launch_bounds__(512) void attn2(const float* __restrict__ el2p,    // [4][2048]
                                             const float* __restrict__ er2p,    // [4][2048]
                                             const int* __restrict__ adj,
                                             const u16* __restrict__ gbt,       // [128][2048]
                                             float* __restrict__ out) {         // [2048][128]
    const int rt = blockIdx.x, sec = blockIdx.y;
    const int i0 = rt * 16;
    const int t = threadIdx.x, lane = t & 63, w = t >> 6;
    const int q = lane >> 4, n = lane & 15;
    const int m = t >> 5, jq = t & 31;
    const int ct = w >> 1, kf2 = w & 1;

    __shared__ u16 ersb[2048];
    __shared__ __align__(16) u16 pl[2][16][264];
    __shared__ float psum_sh[16];
    __shared__ float osh[4][16][16];
    __shared__ float wmax[8];
    __shared__ float mxsh;

    float4 a0 = *(const float4*)(er2p + t * 4);
    float4 a1 = *(const float4*)(er2p + NN + t * 4);
    float4 a2 = *(const float4*)(er2p + 2 * NN + t * 4);
    float4 a3 = *(const float4*)(er2p + 3 * NN + t * 4);
    float4 v0;
    v0.x = ((a0.x + a1.x) + (a2.x + a3.x));
    v0.y = ((a0.y + a1.y) + (a2.y + a3.y));
    v0.z = ((a0.z + a1.z) + (a2.z + a3.z));
    v0.w = ((a0.w + a1.w) + (a2.w + a3.w));
    uint2 c0;
    c0.x = pk2(v0.x, v0.y); c0.y = pk2(v0.z, v0.w);
    *(uint2*)&ersb[t * 4] = c0;
    float m0 = fmaxf(fmaxf(v0.x, v0.y), fmaxf(v0.z, v0.w));
#pragma unroll
    for (int off = 32; off; off >>= 1) m0 = fmaxf(m0, __shfl_xor(m0, off));
    if (lane == 0) wmax[w] = m0;
    __syncthreads();
    if (t == 0) {
        float mm = wmax[0];
#pragma unroll
        for (int ww = 1; ww < 8; ++ww) mm = fmaxf(mm, wmax[ww]);
        mxsh = mm;
    }
    __syncthreads();

    const float elv = el2p[i0 + m] + el2p[NN + i0 + m] + el2p[2 * NN + i0 + m] + el2p[3 * NN + i0 + m];
    float mm2 = elv + mxsh;
    const float mxv = fmaxf(mm2, 0.2f * mm2);
    float ps = 0.f;
    const int* adjrow = adj + (size_t)(i0 + m) * NN;

    auto stage = [&](int tl, int nb) {
        int4 av0 = *(const int4*)(adjrow + tl * 256 + jq * 4);
        int4 av1 = *(const int4*)(adjrow + tl * 256 + 128 + jq * 4);
#pragma unroll
        for (int sub = 0; sub < 2; ++sub) {
            int4 av = sub ? av1 : av0;
            unsigned bits = (unsigned)(av.x != 0) | ((unsigned)(av.y != 0) << 1) |
                            ((unsigned)(av.z != 0) << 2) | ((unsigned)(av.w != 0) << 3);
            const int jo = tl * 256 + sub * 128 + jq * 4;
            uint2 raw = *(const uint2*)&ersb[jo];
            float e0 = __uint_as_float(raw.x << 16);
            float e1 = __uint_as_float(raw.x & 0xFFFF0000u);
            float e2 = __uint_as_float(raw.y << 16);
            float e3 = __uint_as_float(raw.y & 0xFFFF0000u);
            float s0 = elv + e0, s1 = elv + e1, s2 = elv + e2, s3 = elv + e3;
            s0 = fmaxf(s0, 0.2f * s0) - mxv;
            s1 = fmaxf(s1, 0.2f * s1) - mxv;
            s2 = fmaxf(s2, 0.2f * s2) - mxv;
            s3 = fmaxf(s3, 0.2f * s3) - mxv;
            float p0 = (bits & 1u) ? __expf(s0) : 0.f;
            float p1 = (bits & 2u) ? __expf(s1) : 0.f;
            float p2 = (bits & 4u) ? __expf(s2) : 0.f;
            float p3 = (bits & 8u) ? __expf(s3) : 0.f;
            ps += (p0 + p1) + (p2 + p3);
            uint2 pkv;
            pkv.x = pk2(p0, p1);
            pkv.y = pk2(p2, p3);
            *(uint2*)&pl[nb][m][sub * 128 + jq * 4] = pkv;
        }
    };

    const int col = sec * 64 + ct * 16 + n;
    const u16* gb = gbt + (size_t)col * NN + kf2 * 128 + q * 8;
    short8 bc0 = *(const short8*)gb;
    short8 bc1 = *(const short8*)(gb + 32);
    short8 bc2 = *(const short8*)(gb + 64);
    short8 bc3 = *(const short8*)(gb + 96);
    f32x4 acc = {0.f, 0.f, 0.f, 0.f};

    stage(0, 0);
    __syncthreads();

    for (int tile = 0; tile < 8; ++tile) {
        short8 bn0 = bc0, bn1 = bc1, bn2 = bc2, bn3 = bc3;
        if (tile < 7) {
            const u16* gq = gb + (tile + 1) * 256;
            bn0 = *(const short8*)gq;
            bn1 = *(const short8*)(gq + 32);
            bn2 = *(const short8*)(gq + 64);
            bn3 = *(const short8*)(gq + 96);
        }
        const u16* ap = &pl[tile & 1][n][kf2 * 128 + q * 8];
        short8 a0v = *(const short8*)ap;
        short8 a1v = *(const short8*)(ap + 32);
        short8 a2v = *(const short8*)(ap + 64);
        short8 a3v = *(const short8*)(ap + 96);
        acc = __builtin_amdgcn_mfma_f32_16x16x32_bf16(a0v, bc0, acc, 0, 0, 0);
        acc = __builtin_amdgcn_mfma_f32_16x16x32_bf16(a1v, bc1, acc, 0, 0, 0);
        acc = __builtin_amdgcn_mfma_f32_16x16x32_bf16(a2v, bc2, acc, 0, 0, 0);
        acc = __builtin_amdgcn_mfma_f32_16x16x32_bf16(a3v, bc3, acc, 0, 0, 0);
        if (tile < 7) stage(tile + 1, (tile + 1) & 1);
        bc0 = bn0; bc1 = bn1; bc2 = bn2; bc3 = bn3;
        __syncthreads();
    }

#pragma unroll
    for (int off = 16; off; off >>= 1) ps += __shfl_down(ps, off, 32);
    if (jq == 0) psum_sh[m] = ps;
    if (kf2 == 1) {
#pragma unroll
        for (int r = 0; r < 4; ++r) osh[ct][q * 4 + r][n] = acc[r];
    }
    __syncthreads();
    if (kf2 == 0) {
#pragma unroll
        for (int r = 0; r < 4; ++r) {
            int mr = q * 4 + r;
            out[(size_t)(i0 + mr) * 128 + col] = (acc[r] + osh[ct][mr][n]) / psum_sh[mr];
        }
    }
}

extern "C" void kernel_launch(void* const* d_in, const int* in_sizes, int n_in,
                              void* d_out, int out_size, void* d_ws, size_t ws_size,
                              hipStream_t stream) {
    const float* x   = (const float*)d_in[0];
    const float* W1  = (const float*)d_in[1];
    const float* a1l = (const float*)d_in[2];
    const float* a1r = (const float*)d_in[3];
    const float* W2  = (const float*)d_in[4];
    const float* a2l = (const float*)d_in[5];
    const float* a2r = (const float*)d_in[6];
    const int* adj = (const int*)d_in[7];

    char* p = (char*)d_ws;
    u16* xb    = (u16*)p;            p += (size_t)NN * 512 * 2;
    u16* w1t   = (u16*)p;            p += (size_t)256 * 512 * 2;
    u16* w2t   = (u16*)p;            p += (size_t)128 * 256 * 2;
    u16* gbt1  = (u16*)p;            p += (size_t)256 * NN * 2;
    u16* hbb   = (u16*)p;            p += (size_t)NN * 256 * 2;
    u16* gbt2  = (u16*)p;            p += (size_t)128 * NN * 2;
    float* el1 = (float*)p;          p += (size_t)NN * 8 * 4;
    float* ert1 = (float*)p;         p += (size_t)8 * NN * 4;
    float* el2p = (float*)p;         p += (size_t)4 * NN * 4;
    float* er2p = (float*)p;         p += (size_t)4 * NN * 4;

    prep<<<448, 256, 0, stream>>>(x, W1, W2, xb, w1t, w2t);

    gemm1<<<1024, 256, 0, stream>>>(xb, w1t, a1l, a1r, gbt1, el1, ert1);
    attn1<<<dim3(128, 4), 512, 0, stream>>>(el1, ert1, adj, gbt1, hbb);

    gemm2<<<dim3(128, 4), 256, 0, stream>>>(hbb, w2t, a2l, a2r, gbt2, el2p, er2p);
    attn2<<<dim3(128, 2), 512, 0, stream>>>(el2p, er2p, adj, gbt2, (float*)d_out);
}

// Round 6
// 122.441 us; speedup vs baseline: 1.0180x; 1.0017x over previous
//
#include <hip/hip_runtime.h>
#include <hip/hip_bf16.h>

#define NN 2048
typedef unsigned short u16;
typedef unsigned long long u64;
typedef __attribute__((ext_vector_type(8))) short short8;
typedef __attribute__((ext_vector_type(4))) float f32x4;

// fp32 -> bf16 bits, RNE (scalar path)
__device__ __forceinline__ unsigned bfb(float x) {
    unsigned u = __float_as_uint(x);
    return (u + 0x7FFFu + ((u >> 16) & 1u)) >> 16;
}
// packed pair via HW cvt (identical RNE bits, 1 instr)
__device__ __forceinline__ unsigned pk2(float a, float b) {
    unsigned r;
    asm("v_cvt_pk_bf16_f32 %0, %1, %2" : "=v"(r) : "v"(a), "v"(b));
    return r;
}

// ---------------- prep: bf16 conversions only (adj handled inline in attn kernels) ----------------
__global__ __launch_bounds__(256) void prep(const float* __restrict__ x,
                                            const float* __restrict__ W1,
                                            const float* __restrict__ W2,
                                            u16* __restrict__ xb, u16* __restrict__ w1t,
                                            u16* __restrict__ w2t) {
    const int b = blockIdx.x;
    const int tid = threadIdx.x;
    if (b < 256) {                           // x: 2048x512 -> bf16
#pragma unroll
        for (int k = 0; k < 4; ++k) {
            int t = (b * 4 + k) * 256 + tid;
            float4 v = ((const float4*)x)[t];
            uint2 o;
            o.x = pk2(v.x, v.y);
            o.y = pk2(v.z, v.w);
            ((uint2*)xb)[t] = o;
        }
    } else if (b < 256 + 128) {              // w1t[c][k] = W1[k][c]
#pragma unroll
        for (int k = 0; k < 4; ++k) {
            int u = ((b - 256) * 4 + k) * 256 + tid;
            int c = u >> 9, kk = u & 511;
            w1t[u] = (u16)bfb(W1[(size_t)kk * 256 + c]);
        }
    } else {                                 // w2t[c][k] = W2[k][c]
#pragma unroll
        for (int k = 0; k < 4; ++k) {
            int u = ((b - 384) * 4 + k) * 256 + tid;
            int c = u >> 8, kk = u & 255;
            w2t[u] = (u16)bfb(W2[(size_t)kk * 128 + c]);
        }
    }
}

// ---------------- gemm1: 16x32 tile, K=512, LDS-staged from compact bf16 (xb, w1t) ----------------
__global__ __launch_bounds__(256) void gemm1(const u16* __restrict__ xb,   // [2048][512]
                                             const u16* __restrict__ w1t,  // [256][512]
                                             const float* __restrict__ al,
                                             const float* __restrict__ ar,
                                             u16* __restrict__ GT,         // [256][2048]
                                             float* __restrict__ el,       // [2048][8]
                                             float* __restrict__ ert) {    // [8][2048]
    const int bid = blockIdx.x;
    const int xcd = bid & 7, idx = bid >> 3;
    const int rt = xcd * 16 + (idx & 15), cs = idx >> 4;
    const int i0 = rt * 16;
    const int t = threadIdx.x, lane = t & 63, w = t >> 6;
    const int q = lane >> 4, n = lane & 15;
    const int ct = w & 1, kh = w >> 1;
    __shared__ __align__(16) u16 As[16][520];   // ^swz layout
    __shared__ __align__(16) u16 Bs[32][520];
    __shared__ float osh[2][16][16];
    __shared__ float pel[2][16], per_[2][16];

    // stage A: rows i0..i0+15 of xb (16KB), coalesced uint2, conflict-free (half-row per wave)
    {
        const uint2* xs = (const uint2*)(xb + (size_t)i0 * 512);
#pragma unroll
        for (int j = 0; j < 8; ++j) {
            uint2 v = xs[j * 256 + t];
            int e = (j * 256 + t) * 4;
            int r = e >> 9, k = e & 511;
            *(uint2*)&As[r][k ^ ((r & 7) << 3)] = v;
        }
    }
    // stage B: rows cs*32..+31 of w1t (32KB), same pattern
    {
        const uint2* bsrc = (const uint2*)(w1t + (size_t)cs * 32 * 512);
#pragma unroll
        for (int j = 0; j < 16; ++j) {
            uint2 v = bsrc[j * 256 + t];
            int e = (j * 256 + t) * 4;
            int r = e >> 9, k = e & 511;
            *(uint2*)&Bs[r][k ^ ((r & 7) << 3)] = v;
        }
    }
    __syncthreads();

    const int an = n, bn = ct * 16 + n;
    const int k0 = kh * 256 + q * 8;
    f32x4 acc = {0.f, 0.f, 0.f, 0.f};
#pragma unroll
    for (int ks = 0; ks < 8; ++ks) {
        short8 a = *(const short8*)&As[an][(k0 + ks * 32) ^ ((an & 7) << 3)];
        short8 bb = *(const short8*)&Bs[bn][(k0 + ks * 32) ^ ((bn & 7) << 3)];
        acc = __builtin_amdgcn_mfma_f32_16x16x32_bf16(a, bb, acc, 0, 0, 0);
    }
    if (kh == 1) {
#pragma unroll
        for (int r = 0; r < 4; ++r) osh[ct][q * 4 + r][n] = acc[r];
    }
    __syncthreads();
    if (kh == 0) {
#pragma unroll
        for (int r = 0; r < 4; ++r) acc[r] += osh[ct][q * 4 + r][n];
        uint2 g0;
        g0.x = pk2(acc[0], acc[1]);
        g0.y = pk2(acc[2], acc[3]);
        *(uint2*)&GT[(size_t)(cs * 32 + ct * 16 + n) * NN + i0 + q * 4] = g0;
        const float alv = al[ct * 16 + n], arv = ar[ct * 16 + n];
#pragma unroll
        for (int r = 0; r < 4; ++r) {
            float ve = acc[r] * alv, vr = acc[r] * arv;
#pragma unroll
            for (int off = 1; off <= 8; off <<= 1) {
                ve += __shfl_xor(ve, off);
                vr += __shfl_xor(vr, off);
            }
            if (n == 0) { pel[ct][q * 4 + r] = ve; per_[ct][q * 4 + r] = vr; }
        }
    }
    __syncthreads();
    if (t < 16) {
        el[(size_t)(i0 + t) * 8 + cs] = pel[0][t] + pel[1][t];
        ert[(size_t)cs * NN + i0 + t] = per_[0][t] + per_[1][t];
    }
}

// ---------------- gemm2: 16x32 tile, K=256, LDS-staged from hbb + w2t ----------------
__global__ __launch_bounds__(256) void gemm2(const u16* __restrict__ A,    // hbb [2048][256] bf16
                                             const u16* __restrict__ w2t,  // [128][256]
                                             const float* __restrict__ al,
                                             const float* __restrict__ ar,
                                             u16* __restrict__ GT,         // [128][2048]
                                             float* __restrict__ el2p,     // [4][2048]
                                             float* __restrict__ er2p) {   // [4][2048]
    const int i0 = blockIdx.x * 16, cs = blockIdx.y;
    const int t = threadIdx.x, lane = t & 63, w = t >> 6;
    const int q = lane >> 4, n = lane & 15;
    const int ct = w & 1, kh = w >> 1;
    __shared__ __align__(16) u16 As[16][264];
    __shared__ __align__(16) u16 Bs[32][264];
    __shared__ float osh[2][16][16];
    __shared__ float pel[2][16], per_[2][16];

    {
        const uint2* hs = (const uint2*)(A + (size_t)i0 * 256);
#pragma unroll
        for (int j = 0; j < 4; ++j) {
            uint2 v = hs[j * 256 + t];
            int e = (j * 256 + t) * 4;
            int r = e >> 8, k = e & 255;
            *(uint2*)&As[r][k ^ ((r & 7) << 3)] = v;
        }
    }
    {
        const uint2* bsrc = (const uint2*)(w2t + (size_t)cs * 32 * 256);
#pragma unroll
        for (int j = 0; j < 8; ++j) {
            uint2 v = bsrc[j * 256 + t];
            int e = (j * 256 + t) * 4;
            int r = e >> 8, k = e & 255;
            *(uint2*)&Bs[r][k ^ ((r & 7) << 3)] = v;
        }
    }
    __syncthreads();

    const int an = n, bn = ct * 16 + n;
    const int k0 = kh * 128 + q * 8;
    f32x4 acc = {0.f, 0.f, 0.f, 0.f};
#pragma unroll
    for (int ks = 0; ks < 4; ++ks) {
        short8 a = *(const short8*)&As[an][(k0 + ks * 32) ^ ((an & 7) << 3)];
        short8 bb = *(const short8*)&Bs[bn][(k0 + ks * 32) ^ ((bn & 7) << 3)];
        acc = __builtin_amdgcn_mfma_f32_16x16x32_bf16(a, bb, acc, 0, 0, 0);
    }
    if (kh == 1) {
#pragma unroll
        for (int r = 0; r < 4; ++r) osh[ct][q * 4 + r][n] = acc[r];
    }
    __syncthreads();
    if (kh == 0) {
#pragma unroll
        for (int r = 0; r < 4; ++r) acc[r] += osh[ct][q * 4 + r][n];
        uint2 g0;
        g0.x = pk2(acc[0], acc[1]);
        g0.y = pk2(acc[2], acc[3]);
        *(uint2*)&GT[(size_t)(cs * 32 + ct * 16 + n) * NN + i0 + q * 4] = g0;
        const float alv = al[cs * 32 + ct * 16 + n], arv = ar[cs * 32 + ct * 16 + n];
#pragma unroll
        for (int r = 0; r < 4; ++r) {
            float ve = acc[r] * alv, vr = acc[r] * arv;
#pragma unroll
            for (int off = 1; off <= 8; off <<= 1) {
                ve += __shfl_xor(ve, off);
                vr += __shfl_xor(vr, off);
            }
            if (n == 0) { pel[ct][q * 4 + r] = ve; per_[ct][q * 4 + r] = vr; }
        }
    }
    __syncthreads();
    if (t < 16) {
        el2p[(size_t)cs * NN + i0 + t] = pel[0][t] + pel[1][t];
        er2p[(size_t)cs * NN + i0 + t] = per_[0][t] + per_[1][t];
    }
}

// ---------------- attn1: 16 rows x 2 heads, 256-j tiles (8 phases); adj inline.
// XCD-swizzled: sec = xcd>>1 (2 XCDs per sec) so each XCD's L2 caches its 256KB gbt section. ----------------
__global__ __launch_bounds__(512, 4) void attn1(const float* __restrict__ el,      // [2048][8]
                                                const float* __restrict__ ert,     // [8][2048]
                                                const int* __restrict__ adj,       // [2048][2048]
                                                const u16* __restrict__ gbt,       // [256][2048]
                                                u16* __restrict__ hbb) {           // [2048][256]
    const int bid = blockIdx.x;                 // 512 linear
    const int xcd = bid & 7, idx = bid >> 3;    // idx 0..63
    const int sec = xcd >> 1;                   // 0..3
    const int rt = (xcd & 1) * 64 + idx;        // 0..127
    const int i0 = rt * 16, h0 = sec * 2;
    const int t = threadIdx.x, lane = t & 63, w = t >> 6;
    const int q = lane >> 4, n = lane & 15;
    const int m = t >> 5, jq = t & 31;
    const int hl = w >> 2, ch = (w >> 1) & 1, kf2 = w & 1;

    __shared__ u16 ersb[2][2048];                     // bf16 er
    __shared__ __align__(16) u16 pl[2][2][16][264];   // [buf][h][m][k]
    __shared__ float psum_sh[16][2];
    __shared__ float osh[2][2][16][16];
    __shared__ float wmax[2][8];
    __shared__ float mxsh[2];

    float4 v0 = *(const float4*)(ert + (size_t)h0 * NN + t * 4);
    float4 v1 = *(const float4*)(ert + (size_t)(h0 + 1) * NN + t * 4);
    uint2 c0, c1;
    c0.x = pk2(v0.x, v0.y); c0.y = pk2(v0.z, v0.w);
    c1.x = pk2(v1.x, v1.y); c1.y = pk2(v1.z, v1.w);
    *(uint2*)&ersb[0][t * 4] = c0;
    *(uint2*)&ersb[1][t * 4] = c1;
    float m0 = fmaxf(fmaxf(v0.x, v0.y), fmaxf(v0.z, v0.w));
    float m1 = fmaxf(fmaxf(v1.x, v1.y), fmaxf(v1.z, v1.w));
#pragma unroll
    for (int off = 32; off; off >>= 1) {
        m0 = fmaxf(m0, __shfl_xor(m0, off));
        m1 = fmaxf(m1, __shfl_xor(m1, off));
    }
    if (lane == 0) { wmax[0][w] = m0; wmax[1][w] = m1; }
    __syncthreads();
    if (t < 2) {
        float mm = wmax[t][0];
#pragma unroll
        for (int ww = 1; ww < 8; ++ww) mm = fmaxf(mm, wmax[t][ww]);
        mxsh[t] = mm;
    }
    __syncthreads();

    float elv[2], mxv[2], ps[2];
#pragma unroll
    for (int h = 0; h < 2; ++h) {
        float e = el[(size_t)(i0 + m) * 8 + h0 + h];
        elv[h] = e;
        float mm = e + mxsh[h];
        mxv[h] = fmaxf(mm, 0.2f * mm);
        ps[h] = 0.f;
    }
    const int* adjrow = adj + (size_t)(i0 + m) * NN;

    auto stage = [&](int tl, int nb) {
        // issue both adj int4 loads first (independent; latency overlaps nibble/VALU work)
        int4 av0 = *(const int4*)(adjrow + tl * 256 + jq * 4);
        int4 av1 = *(const int4*)(adjrow + tl * 256 + 128 + jq * 4);
#pragma unroll
        for (int sub = 0; sub < 2; ++sub) {
            int4 av = sub ? av1 : av0;
            unsigned bits = (unsigned)(av.x != 0) | ((unsigned)(av.y != 0) << 1) |
                            ((unsigned)(av.z != 0) << 2) | ((unsigned)(av.w != 0) << 3);
            const int jo = tl * 256 + sub * 128 + jq * 4;
            uint2 raw0 = *(const uint2*)&ersb[0][jo];
            uint2 raw1 = *(const uint2*)&ersb[1][jo];
#pragma unroll
            for (int h = 0; h < 2; ++h) {
                uint2 raw = h ? raw1 : raw0;
                float e0 = __uint_as_float(raw.x << 16);
                float e1 = __uint_as_float(raw.x & 0xFFFF0000u);
                float e2 = __uint_as_float(raw.y << 16);
                float e3 = __uint_as_float(raw.y & 0xFFFF0000u);
                float s0 = elv[h] + e0, s1 = elv[h] + e1, s2 = elv[h] + e2, s3 = elv[h] + e3;
                s0 = fmaxf(s0, 0.2f * s0) - mxv[h];
                s1 = fmaxf(s1, 0.2f * s1) - mxv[h];
                s2 = fmaxf(s2, 0.2f * s2) - mxv[h];
                s3 = fmaxf(s3, 0.2f * s3) - mxv[h];
                float p0 = (bits & 1u) ? __expf(s0) : 0.f;
                float p1 = (bits & 2u) ? __expf(s1) : 0.f;
                float p2 = (bits & 4u) ? __expf(s2) : 0.f;
                float p3 = (bits & 8u) ? __expf(s3) : 0.f;
                ps[h] += (p0 + p1) + (p2 + p3);
                uint2 pkv;
                pkv.x = pk2(p0, p1);
                pkv.y = pk2(p2, p3);
                *(uint2*)&pl[nb][h][m][sub * 128 + jq * 4] = pkv;
            }
        }
    };

    const int col = sec * 64 + hl * 32 + ch * 16 + n;
    const u16* gb = gbt + (size_t)col * NN + kf2 * 128 + q * 8;
    short8 bc0 = *(const short8*)gb;
    short8 bc1 = *(const short8*)(gb + 32);
    short8 bc2 = *(const short8*)(gb + 64);
    short8 bc3 = *(const short8*)(gb + 96);
    f32x4 acc = {0.f, 0.f, 0.f, 0.f};

    stage(0, 0);
    __syncthreads();

    for (int tile = 0; tile < 8; ++tile) {
        short8 bn0 = bc0, bn1 = bc1, bn2 = bc2, bn3 = bc3;
        if (tile < 7) {
            const u16* gq = gb + (tile + 1) * 256;
            bn0 = *(const short8*)gq;
            bn1 = *(const short8*)(gq + 32);
            bn2 = *(const short8*)(gq + 64);
            bn3 = *(const short8*)(gq + 96);
        }
        const u16* ap = &pl[tile & 1][hl][n][kf2 * 128 + q * 8];
        short8 a0 = *(const short8*)ap;
        short8 a1 = *(const short8*)(ap + 32);
        short8 a2 = *(const short8*)(ap + 64);
        short8 a3 = *(const short8*)(ap + 96);
        acc = __builtin_amdgcn_mfma_f32_16x16x32_bf16(a0, bc0, acc, 0, 0, 0);
        acc = __builtin_amdgcn_mfma_f32_16x16x32_bf16(a1, bc1, acc, 0, 0, 0);
        acc = __builtin_amdgcn_mfma_f32_16x16x32_bf16(a2, bc2, acc, 0, 0, 0);
        acc = __builtin_amdgcn_mfma_f32_16x16x32_bf16(a3, bc3, acc, 0, 0, 0);
        if (tile < 7) stage(tile + 1, (tile + 1) & 1);
        bc0 = bn0; bc1 = bn1; bc2 = bn2; bc3 = bn3;
        __syncthreads();
    }

#pragma unroll
    for (int h = 0; h < 2; ++h) {
        float v = ps[h];
#pragma unroll
        for (int off = 16; off; off >>= 1) v += __shfl_down(v, off, 32);
        if (jq == 0) psum_sh[m][h] = v;
    }
    if (kf2 == 1) {
#pragma unroll
        for (int r = 0; r < 4; ++r) osh[hl][ch][q * 4 + r][n] = acc[r];
    }
    __syncthreads();
    if (kf2 == 0) {
#pragma unroll
        for (int r = 0; r < 4; ++r) {
            int mr = q * 4 + r;
            float o = (acc[r] + osh[hl][ch][mr][n]) / psum_sh[mr][hl];
            o = o > 0.f ? o : (__expf(o) - 1.f); // ELU
            hbb[(size_t)(i0 + mr) * 256 + col] = (u16)bfb(o);
        }
    }
}

// ---------------- attn2: 16 rows x 64 cols, 256-j tiles (8 phases); adj inline.
// XCD-swizzled: sec = xcd>>2 (4 XCDs per sec). ----------------
__global__ __launch_bounds__(512) void attn2(const float* __restrict__ el2p,    // [4][2048]
                                             const float* __restrict__ er2p,    // [4][2048]
                                             const int* __restrict__ adj,
                                             const u16* __restrict__ gbt,       // [128][2048]
                                             float* __restrict__ out) {         // [2048][128]
    const int bid = blockIdx.x;                 // 256 linear
    const int xcd = bid & 7, idx = bid >> 3;    // idx 0..31
    const int sec = xcd >> 2;                   // 0..1
    const int rt = (xcd & 3) * 32 + idx;        // 0..127
    const int i0 = rt * 16;
    const int t = threadIdx.x, lane = t & 63, w = t >> 6;
    const int q = lane >> 4, n = lane & 15;
    const int m = t >> 5, jq = t & 31;
    const int ct = w >> 1, kf2 = w & 1;

    __shared__ u16 ersb[2048];
    __shared__ __align__(16) u16 pl[2][16][264];
    __shared__ float psum_sh[16];
    __shared__ float osh[4][16][16];
    __shared__ float wmax[8];
    __shared__ float mxsh;

    float4 a0 = *(const float4*)(er2p + t * 4);
    float4 a1 = *(const float4*)(er2p + NN + t * 4);
    float4 a2 = *(const float4*)(er2p + 2 * NN + t * 4);
    float4 a3 = *(const float4*)(er2p + 3 * NN + t * 4);
    float4 v0;
    v0.x = ((a0.x + a1.x) + (a2.x + a3.x));
    v0.y = ((a0.y + a1.y) + (a2.y + a3.y));
    v0.z = ((a0.z + a1.z) + (a2.z + a3.z));
    v0.w = ((a0.w + a1.w) + (a2.w + a3.w));
    uint2 c0;
    c0.x = pk2(v0.x, v0.y); c0.y = pk2(v0.z, v0.w);
    *(uint2*)&ersb[t * 4] = c0;
    float m0 = fmaxf(fmaxf(v0.x, v0.y), fmaxf(v0.z, v0.w));
#pragma unroll
    for (int off = 32; off; off >>= 1) m0 = fmaxf(m0, __shfl_xor(m0, off));
    if (lane == 0) wmax[w] = m0;
    __syncthreads();
    if (t == 0) {
        float mm = wmax[0];
#pragma unroll
        for (int ww = 1; ww < 8; ++ww) mm = fmaxf(mm, wmax[ww]);
        mxsh = mm;
    }
    __syncthreads();

    const float elv = el2p[i0 + m] + el2p[NN + i0 + m] + el2p[2 * NN + i0 + m] + el2p[3 * NN + i0 + m];
    float mm2 = elv + mxsh;
    const float mxv = fmaxf(mm2, 0.2f * mm2);
    float ps = 0.f;
    const int* adjrow = adj + (size_t)(i0 + m) * NN;

    auto stage = [&](int tl, int nb) {
        int4 av0 = *(const int4*)(adjrow + tl * 256 + jq * 4);
        int4 av1 = *(const int4*)(adjrow + tl * 256 + 128 + jq * 4);
#pragma unroll
        for (int sub = 0; sub < 2; ++sub) {
            int4 av = sub ? av1 : av0;
            unsigned bits = (unsigned)(av.x != 0) | ((unsigned)(av.y != 0) << 1) |
                            ((unsigned)(av.z != 0) << 2) | ((unsigned)(av.w != 0) << 3);
            const int jo = tl * 256 + sub * 128 + jq * 4;
            uint2 raw = *(const uint2*)&ersb[jo];
            float e0 = __uint_as_float(raw.x << 16);
            float e1 = __uint_as_float(raw.x & 0xFFFF0000u);
            float e2 = __uint_as_float(raw.y << 16);
            float e3 = __uint_as_float(raw.y & 0xFFFF0000u);
            float s0 = elv + e0, s1 = elv + e1, s2 = elv + e2, s3 = elv + e3;
            s0 = fmaxf(s0, 0.2f * s0) - mxv;
            s1 = fmaxf(s1, 0.2f * s1) - mxv;
            s2 = fmaxf(s2, 0.2f * s2) - mxv;
            s3 = fmaxf(s3, 0.2f * s3) - mxv;
            float p0 = (bits & 1u) ? __expf(s0) : 0.f;
            float p1 = (bits & 2u) ? __expf(s1) : 0.f;
            float p2 = (bits & 4u) ? __expf(s2) : 0.f;
            float p3 = (bits & 8u) ? __expf(s3) : 0.f;
            ps += (p0 + p1) + (p2 + p3);
            uint2 pkv;
            pkv.x = pk2(p0, p1);
            pkv.y = pk2(p2, p3);
            *(uint2*)&pl[nb][m][sub * 128 + jq * 4] = pkv;
        }
    };

    const int col = sec * 64 + ct * 16 + n;
    const u16* gb = gbt + (size_t)col * NN + kf2 * 128 + q * 8;
    short8 bc0 = *(const short8*)gb;
    short8 bc1 = *(const short8*)(gb + 32);
    short8 bc2 = *(const short8*)(gb + 64);
    short8 bc3 = *(const short8*)(gb + 96);
    f32x4 acc = {0.f, 0.f, 0.f, 0.f};

    stage(0, 0);
    __syncthreads();

    for (int tile = 0; tile < 8; ++tile) {
        short8 bn0 = bc0, bn1 = bc1, bn2 = bc2, bn3 = bc3;
        if (tile < 7) {
            const u16* gq = gb + (tile + 1) * 256;
            bn0 = *(const short8*)gq;
            bn1 = *(const short8*)(gq + 32);
            bn2 = *(const short8*)(gq + 64);
            bn3 = *(const short8*)(gq + 96);
        }
        const u16* ap = &pl[tile & 1][n][kf2 * 128 + q * 8];
        short8 a0v = *(const short8*)ap;
        short8 a1v = *(const short8*)(ap + 32);
        short8 a2v = *(const short8*)(ap + 64);
        short8 a3v = *(const short8*)(ap + 96);
        acc = __builtin_amdgcn_mfma_f32_16x16x32_bf16(a0v, bc0, acc, 0, 0, 0);
        acc = __builtin_amdgcn_mfma_f32_16x16x32_bf16(a1v, bc1, acc, 0, 0, 0);
        acc = __builtin_amdgcn_mfma_f32_16x16x32_bf16(a2v, bc2, acc, 0, 0, 0);
        acc = __builtin_amdgcn_mfma_f32_16x16x32_bf16(a3v, bc3, acc, 0, 0, 0);
        if (tile < 7) stage(tile + 1, (tile + 1) & 1);
        bc0 = bn0; bc1 = bn1; bc2 = bn2; bc3 = bn3;
        __syncthreads();
    }

#pragma unroll
    for (int off = 16; off; off >>= 1) ps += __shfl_down(ps, off, 32);
    if (jq == 0) psum_sh[m] = ps;
    if (kf2 == 1) {
#pragma unroll
        for (int r = 0; r < 4; ++r) osh[ct][q * 4 + r][n] = acc[r];
    }
    __syncthreads();
    if (kf2 == 0) {
#pragma unroll
        for (int r = 0; r < 4; ++r) {
            int mr = q * 4 + r;
            out[(size_t)(i0 + mr) * 128 + col] = (acc[r] + osh[ct][mr][n]) / psum_sh[mr];
        }
    }
}

extern "C" void kernel_launch(void* const* d_in, const int* in_sizes, int n_in,
                              void* d_out, int out_size, void* d_ws, size_t ws_size,
                              hipStream_t stream) {
    const float* x   = (const float*)d_in[0];
    const float* W1  = (const float*)d_in[1];
    const float* a1l = (const float*)d_in[2];
    const float* a1r = (const float*)d_in[3];
    const float* W2  = (const float*)d_in[4];
    const float* a2l = (const float*)d_in[5];
    const float* a2r = (const float*)d_in[6];
    const int* adj = (const int*)d_in[7];

    char* p = (char*)d_ws;
    u16* xb    = (u16*)p;            p += (size_t)NN * 512 * 2;
    u16* w1t   = (u16*)p;            p += (size_t)256 * 512 * 2;
    u16* w2t   = (u16*)p;            p += (size_t)128 * 256 * 2;
    u16* gbt1  = (u16*)p;            p += (size_t)256 * NN * 2;
    u16* hbb   = (u16*)p;            p += (size_t)NN * 256 * 2;
    u16* gbt2  = (u16*)p;            p += (size_t)128 * NN * 2;
    float* el1 = (float*)p;          p += (size_t)NN * 8 * 4;
    float* ert1 = (float*)p;         p += (size_t)8 * NN * 4;
    float* el2p = (float*)p;         p += (size_t)4 * NN * 4;
    float* er2p = (float*)p;         p += (size_t)4 * NN * 4;

    prep<<<448, 256, 0, stream>>>(x, W1, W2, xb, w1t, w2t);

    gemm1<<<1024, 256, 0, stream>>>(xb, w1t, a1l, a1r, gbt1, el1, ert1);
    attn1<<<512, 512, 0, stream>>>(el1, ert1, adj, gbt1, hbb);

    gemm2<<<dim3(128, 4), 256, 0, stream>>>(hbb, w2t, a2l, a2r, gbt2, el2p, er2p);
    attn2<<<256, 512, 0, stream>>>(el2p, er2p, adj, gbt2, (float*)d_out);
}